// Round 6
// baseline (650.476 us; speedup 1.0000x reference)
//
#include <hip/hip_runtime.h>

#define N_   128
#define C_   12
#define L_   2048
#define H_   32
#define K_   8
#define CP_  6
#define KW_  9
#define FEAT_ 8192   // D*DIV*2*H*K

// s_buf serves two lives: [0..3071] padded conv input, then [256][17] reduce matrix
#define SBUF_ 4352

template<int DIL, bool GUARD>
__device__ __forceinline__ void conv_phase(const float* __restrict__ s,
                                           const float* __restrict__ wr,
                                           float* __restrict__ cx,
                                           int* __restrict__ cn,
                                           const int tid, const int Lout)
{
    #pragma unroll 2
    for (int i = 0; i < 8; ++i) {
        const int t = tid + (i << 8);
        if (GUARD && t >= Lout) continue;
        float a0 = 0.f, a1 = 0.f, a2 = 0.f, a3 = 0.f,
              a4 = 0.f, a5 = 0.f, a6 = 0.f, a7 = 0.f;
        #pragma unroll
        for (int w = 0; w < KW_; ++w) {
            const float v = s[t + w * DIL];   // imm offset: w*DIL*4 <= 4096
            a0 = fmaf(v, wr[0 * KW_ + w], a0);
            a1 = fmaf(v, wr[1 * KW_ + w], a1);
            a2 = fmaf(v, wr[2 * KW_ + w], a2);
            a3 = fmaf(v, wr[3 * KW_ + w], a3);
            a4 = fmaf(v, wr[4 * KW_ + w], a4);
            a5 = fmaf(v, wr[5 * KW_ + w], a5);
            a6 = fmaf(v, wr[6 * KW_ + w], a6);
            a7 = fmaf(v, wr[7 * KW_ + w], a7);
        }
        const float mx = fmaxf(fmaxf(fmaxf(a0, a1), fmaxf(a2, a3)),
                               fmaxf(fmaxf(a4, a5), fmaxf(a6, a7)));
        const float mn = fminf(fminf(fminf(a0, a1), fminf(a2, a3)),
                               fminf(fminf(a4, a5), fminf(a6, a7)));
        // equality scatter (exact interior ties ~impossible: distinct random taps)
        cx[0] += (a0 == mx) ? a0 : 0.f;  cn[0] += (a0 == mn);
        cx[1] += (a1 == mx) ? a1 : 0.f;  cn[1] += (a1 == mn);
        cx[2] += (a2 == mx) ? a2 : 0.f;  cn[2] += (a2 == mn);
        cx[3] += (a3 == mx) ? a3 : 0.f;  cn[3] += (a3 == mn);
        cx[4] += (a4 == mx) ? a4 : 0.f;  cn[4] += (a4 == mn);
        cx[5] += (a5 == mx) ? a5 : 0.f;  cn[5] += (a5 == mn);
        cx[6] += (a6 == mx) ? a6 : 0.f;  cn[6] += (a6 == mn);
        cx[7] += (a7 == mx) ? a7 : 0.f;  cn[7] += (a7 == mn);
    }
}

__global__ __launch_bounds__(256, 4) void hydra_kernel(
    const float* __restrict__ X,   // [N, C, L]
    const float* __restrict__ W,   // [D, DIV, K*H, 1, KW]
    const int*   __restrict__ I,   // [D, DIV, H, CP]
    float* __restrict__ out)       // [N, FEAT]
{
    __shared__ float s_buf[SBUF_];

    const int tid  = threadIdx.x;
    const int b    = blockIdx.x;
    const int h    = b & (H_ - 1);
    const int comb = (b >> 5) & 15;     // di*2 + df
    const int n    = b >> 9;
    const int df   = comb & 1;
    const int di   = comb >> 1;
    const int d    = 1 << di;
    const int pad  = 4 * d;

    // ---- zero init (3072 floats as float4) ----
    {
        const float4 z4 = {0.f, 0.f, 0.f, 0.f};
        float4* sb4 = (float4*)s_buf;
        sb4[tid]       = z4;
        sb4[tid + 256] = z4;
        sb4[tid + 512] = z4;
    }

    // block-uniform channel indices / weights (scalar loads -> SGPRs)
    const int* Ib = I + (comb * H_ + h) * CP_;
    const int c0 = Ib[0], c1 = Ib[1], c2 = Ib[2],
              c3 = Ib[3], c4 = Ib[4], c5 = Ib[5];
    const float* Xn = X + (size_t)n * (C_ * L_);
    const float* xs0 = Xn + c0 * L_;
    const float* xs1 = Xn + c1 * L_;
    const float* xs2 = Xn + c2 * L_;
    const float* xs3 = Xn + c3 * L_;
    const float* xs4 = Xn + c4 * L_;
    const float* xs5 = Xn + c5 * L_;

    const float* Wb = W + (size_t)(comb * (K_ * H_) + h * K_) * KW_;
    float wr[K_ * KW_];
    #pragma unroll
    for (int q = 0; q < K_ * KW_; ++q) wr[q] = Wb[q];

    __syncthreads();   // zeros visible

    // ---- staging: 8 consecutive positions per thread, float4 loads ----
    {
        const int base = tid * 8;
        float o[8] = {0.f, 0.f, 0.f, 0.f, 0.f, 0.f, 0.f, 0.f};
        const float* xp_arr[6] = {xs0, xs1, xs2, xs3, xs4, xs5};
        if (df == 0) {
            #pragma unroll
            for (int u = 0; u < 6; ++u) {
                const float* xp = xp_arr[u] + base;
                const float4 lo = *(const float4*)xp;
                const float4 hi = *(const float4*)(xp + 4);
                o[0] += lo.x; o[1] += lo.y; o[2] += lo.z; o[3] += lo.w;
                o[4] += hi.x; o[5] += hi.y; o[6] += hi.z; o[7] += hi.w;
            }
        } else {
            #pragma unroll
            for (int u = 0; u < 6; ++u) {
                const float* xp = xp_arr[u] + base;
                const float4 lo = *(const float4*)xp;
                const float4 hi = *(const float4*)(xp + 4);
                const float v8 = (tid < 255) ? xp[8] : 0.0f;  // avoid OOB
                o[0] += lo.y - lo.x; o[1] += lo.z - lo.y;
                o[2] += lo.w - lo.z; o[3] += hi.x - lo.w;
                o[4] += hi.y - hi.x; o[5] += hi.z - hi.y;
                o[6] += hi.w - hi.z; o[7] += v8   - hi.w;
            }
            if (tid == 255) o[7] = 0.0f;   // t'=2047 not in Lsrc=2047
        }
        float4 w0 = {o[0], o[1], o[2], o[3]};
        float4 w1 = {o[4], o[5], o[6], o[7]};
        *(float4*)(&s_buf[pad + base])     = w0;
        *(float4*)(&s_buf[pad + base + 4]) = w1;
    }

    __syncthreads();

    // ---- conv + equality-scatter (templated dilation) ----
    float cx[K_] = {0.f, 0.f, 0.f, 0.f, 0.f, 0.f, 0.f, 0.f};
    int   cn[K_] = {0, 0, 0, 0, 0, 0, 0, 0};
    const int Lout = L_ - df;

    switch (comb) {
        case  0: conv_phase<  1, false>(s_buf, wr, cx, cn, tid, Lout); break;
        case  1: conv_phase<  1, true >(s_buf, wr, cx, cn, tid, Lout); break;
        case  2: conv_phase<  2, false>(s_buf, wr, cx, cn, tid, Lout); break;
        case  3: conv_phase<  2, true >(s_buf, wr, cx, cn, tid, Lout); break;
        case  4: conv_phase<  4, false>(s_buf, wr, cx, cn, tid, Lout); break;
        case  5: conv_phase<  4, true >(s_buf, wr, cx, cn, tid, Lout); break;
        case  6: conv_phase<  8, false>(s_buf, wr, cx, cn, tid, Lout); break;
        case  7: conv_phase<  8, true >(s_buf, wr, cx, cn, tid, Lout); break;
        case  8: conv_phase< 16, false>(s_buf, wr, cx, cn, tid, Lout); break;
        case  9: conv_phase< 16, true >(s_buf, wr, cx, cn, tid, Lout); break;
        case 10: conv_phase< 32, false>(s_buf, wr, cx, cn, tid, Lout); break;
        case 11: conv_phase< 32, true >(s_buf, wr, cx, cn, tid, Lout); break;
        case 12: conv_phase< 64, false>(s_buf, wr, cx, cn, tid, Lout); break;
        case 13: conv_phase< 64, true >(s_buf, wr, cx, cn, tid, Lout); break;
        case 14: conv_phase<128, false>(s_buf, wr, cx, cn, tid, Lout); break;
        default: conv_phase<128, true >(s_buf, wr, cx, cn, tid, Lout); break;
    }

    __syncthreads();   // conv done reading s_buf

    // ---- LDS-matrix block reduction: s_buf reused as [256][17] ----
    #pragma unroll
    for (int k = 0; k < K_; ++k) {
        s_buf[tid * 17 + k]      = cx[k];
        s_buf[tid * 17 + 8 + k]  = (float)cn[k];
    }
    __syncthreads();

    {
        const int r = tid >> 4;    // which accumulator (0..15)
        const int c = tid & 15;    // which 16-thread chunk
        float p = 0.f;
        #pragma unroll
        for (int u = 0; u < 16; ++u)
            p += s_buf[(c * 16 + u) * 17 + r];
        #pragma unroll
        for (int off = 1; off < 16; off <<= 1)
            p += __shfl_xor(p, off, 64);
        if (c == 0) {
            const int s = r >> 3;      // 0 = cmax, 1 = cmin
            const int k = r & 7;
            out[(size_t)n * FEAT_ + (comb * 2 + s) * (H_ * K_) + h * K_ + k] = p;
        }
    }
}

extern "C" void kernel_launch(void* const* d_in, const int* in_sizes, int n_in,
                              void* d_out, int out_size, void* d_ws, size_t ws_size,
                              hipStream_t stream) {
    const float* X = (const float*)d_in[0];
    const float* W = (const float*)d_in[1];
    const int*   I = (const int*)d_in[2];
    float* out = (float*)d_out;

    const int blocks = N_ * 16 * H_;   // 65536: (n, di, df, h)
    hipLaunchKernelGGL(hydra_kernel, dim3(blocks), dim3(256), 0, stream,
                       X, W, I, out);
}

// Round 7
// 592.510 us; speedup vs baseline: 1.0978x; 1.0978x over previous
//
#include <hip/hip_runtime.h>

#define N_   128
#define C_   12
#define L_   2048
#define H_   32
#define K_   8
#define CP_  6
#define KW_  9
#define FEAT_ 8192   // D*DIV*2*H*K

// s_buf: [0..3071] padded conv input, then reused as [256][17] reduce matrix
#define SBUF_ 4352

template<int DIL, bool GUARD>
__device__ __forceinline__ void conv_phase(const float* __restrict__ s,
                                           const float* __restrict__ wr,
                                           float* __restrict__ cx,
                                           int* __restrict__ cn,
                                           const int tid)
{
    #pragma unroll
    for (int i = 0; i < 8; ++i) {
        const int t = tid + (i << 8);
        // GUARD (df=1, Lout=2047): only t=2047 (tid=255, i=7) is out of range
        if (GUARD && (i == 7) && (tid == 255)) continue;

        float a0 = 0.f, a1 = 0.f, a2 = 0.f, a3 = 0.f,
              a4 = 0.f, a5 = 0.f, a6 = 0.f, a7 = 0.f;
        #pragma unroll
        for (int w = 0; w < KW_; ++w) {
            const float v = s[t + w * DIL];   // lane-stride-1: conflict-free
            a0 = fmaf(v, wr[0 * KW_ + w], a0);
            a1 = fmaf(v, wr[1 * KW_ + w], a1);
            a2 = fmaf(v, wr[2 * KW_ + w], a2);
            a3 = fmaf(v, wr[3 * KW_ + w], a3);
            a4 = fmaf(v, wr[4 * KW_ + w], a4);
            a5 = fmaf(v, wr[5 * KW_ + w], a5);
            a6 = fmaf(v, wr[6 * KW_ + w], a6);
            a7 = fmaf(v, wr[7 * KW_ + w], a7);
        }
        // v_max3/v_min3-fusable trees: fmaxf(fmaxf(a,b),c) patterns
        const float mxa = fmaxf(fmaxf(a0, a1), a2);
        const float mxb = fmaxf(fmaxf(a3, a4), a5);
        const float mxc = fmaxf(fmaxf(a6, a7), mxa);
        const float mx  = fmaxf(mxb, mxc);
        const float mna = fminf(fminf(a0, a1), a2);
        const float mnb = fminf(fminf(a3, a4), a5);
        const float mnc = fminf(fminf(a6, a7), mna);
        const float mn  = fminf(mnb, mnc);
        // equality scatter (exact ties across distinct random taps: measure-zero)
        cx[0] += (a0 == mx) ? a0 : 0.f;  cn[0] += (a0 == mn);
        cx[1] += (a1 == mx) ? a1 : 0.f;  cn[1] += (a1 == mn);
        cx[2] += (a2 == mx) ? a2 : 0.f;  cn[2] += (a2 == mn);
        cx[3] += (a3 == mx) ? a3 : 0.f;  cn[3] += (a3 == mn);
        cx[4] += (a4 == mx) ? a4 : 0.f;  cn[4] += (a4 == mn);
        cx[5] += (a5 == mx) ? a5 : 0.f;  cn[5] += (a5 == mn);
        cx[6] += (a6 == mx) ? a6 : 0.f;  cn[6] += (a6 == mn);
        cx[7] += (a7 == mx) ? a7 : 0.f;  cn[7] += (a7 == mn);
    }
}

__global__ __launch_bounds__(256, 4) void hydra_kernel(
    const float* __restrict__ X,   // [N, C, L]
    const float* __restrict__ W,   // [D, DIV, K*H, 1, KW]
    const int*   __restrict__ I,   // [D, DIV, H, CP]
    float* __restrict__ out)       // [N, FEAT]
{
    __shared__ float s_buf[SBUF_];

    const int tid  = threadIdx.x;
    const int b    = blockIdx.x;
    const int h    = b & (H_ - 1);
    const int comb = (b >> 5) & 15;     // di*2 + df
    const int n    = b >> 9;
    const int df   = comb & 1;
    const int di   = comb >> 1;
    const int d    = 1 << di;
    const int Lsrc = L_ - df;           // 2048 or 2047
    const int pad  = 4 * d;

    // ---- zero init, stride-1 (conflict-free, proven in R3) ----
    #pragma unroll
    for (int i = 0; i < 12; ++i) s_buf[tid + i * 256] = 0.0f;

    // block-uniform channel indices (scalarized)
    const int* Ib = I + (comb * H_ + h) * CP_;
    const int c0 = Ib[0], c1 = Ib[1], c2 = Ib[2],
              c3 = Ib[3], c4 = Ib[4], c5 = Ib[5];
    const float* Xn = X + (size_t)n * (C_ * L_);
    const float* x0 = Xn + c0 * L_;
    const float* x1 = Xn + c1 * L_;
    const float* x2 = Xn + c2 * L_;
    const float* x3 = Xn + c3 * L_;
    const float* x4 = Xn + c4 * L_;
    const float* x5 = Xn + c5 * L_;

    // block-uniform weights -> SGPRs (s_load)
    const float* Wb = W + (size_t)(comb * (K_ * H_) + h * K_) * KW_;
    float wr[K_ * KW_];
    #pragma unroll
    for (int q = 0; q < K_ * KW_; ++q) wr[q] = Wb[q];

    __syncthreads();   // zeros visible

    // ---- staging, R3-style stride-256 (coalesced global, stride-1 LDS) ----
    for (int t = tid; t < Lsrc; t += 256) {
        float v;
        if (df == 0) {
            v = x0[t] + x1[t] + x2[t] + x3[t] + x4[t] + x5[t];
        } else {
            v = (x0[t + 1] - x0[t]) + (x1[t + 1] - x1[t]) + (x2[t + 1] - x2[t])
              + (x3[t + 1] - x3[t]) + (x4[t + 1] - x4[t]) + (x5[t + 1] - x5[t]);
        }
        s_buf[pad + t] = v;
    }

    __syncthreads();

    // ---- conv + equality-scatter (templated dilation) ----
    float cx[K_] = {0.f, 0.f, 0.f, 0.f, 0.f, 0.f, 0.f, 0.f};
    int   cn[K_] = {0, 0, 0, 0, 0, 0, 0, 0};

    switch (comb) {
        case  0: conv_phase<  1, false>(s_buf, wr, cx, cn, tid); break;
        case  1: conv_phase<  1, true >(s_buf, wr, cx, cn, tid); break;
        case  2: conv_phase<  2, false>(s_buf, wr, cx, cn, tid); break;
        case  3: conv_phase<  2, true >(s_buf, wr, cx, cn, tid); break;
        case  4: conv_phase<  4, false>(s_buf, wr, cx, cn, tid); break;
        case  5: conv_phase<  4, true >(s_buf, wr, cx, cn, tid); break;
        case  6: conv_phase<  8, false>(s_buf, wr, cx, cn, tid); break;
        case  7: conv_phase<  8, true >(s_buf, wr, cx, cn, tid); break;
        case  8: conv_phase< 16, false>(s_buf, wr, cx, cn, tid); break;
        case  9: conv_phase< 16, true >(s_buf, wr, cx, cn, tid); break;
        case 10: conv_phase< 32, false>(s_buf, wr, cx, cn, tid); break;
        case 11: conv_phase< 32, true >(s_buf, wr, cx, cn, tid); break;
        case 12: conv_phase< 64, false>(s_buf, wr, cx, cn, tid); break;
        case 13: conv_phase< 64, true >(s_buf, wr, cx, cn, tid); break;
        case 14: conv_phase<128, false>(s_buf, wr, cx, cn, tid); break;
        default: conv_phase<128, true >(s_buf, wr, cx, cn, tid); break;
    }

    __syncthreads();   // conv done reading s_buf

    // ---- LDS-matrix block reduction: s_buf reused as [256][17] ----
    #pragma unroll
    for (int k = 0; k < K_; ++k) {
        s_buf[tid * 17 + k]      = cx[k];        // stride-17: 2 lanes/bank, free
        s_buf[tid * 17 + 8 + k]  = (float)cn[k];
    }
    __syncthreads();

    {
        const int r = tid >> 4;    // which accumulator (0..15)
        const int c = tid & 15;    // which 16-thread chunk
        float p = 0.f;
        #pragma unroll
        for (int u = 0; u < 16; ++u)
            p += s_buf[(c * 16 + u) * 17 + r];
        #pragma unroll
        for (int off = 1; off < 16; off <<= 1)
            p += __shfl_xor(p, off, 64);
        if (c == 0) {
            const int s = r >> 3;      // 0 = cmax, 1 = cmin
            const int k = r & 7;
            out[(size_t)n * FEAT_ + (comb * 2 + s) * (H_ * K_) + h * K_ + k] = p;
        }
    }
}

extern "C" void kernel_launch(void* const* d_in, const int* in_sizes, int n_in,
                              void* d_out, int out_size, void* d_ws, size_t ws_size,
                              hipStream_t stream) {
    const float* X = (const float*)d_in[0];
    const float* W = (const float*)d_in[1];
    const int*   I = (const int*)d_in[2];
    float* out = (float*)d_out;

    const int blocks = N_ * 16 * H_;   // 65536: (n, di, df, h)
    hipLaunchKernelGGL(hydra_kernel, dim3(blocks), dim3(256), 0, stream,
                       X, W, I, out);
}